// Round 5
// baseline (446.392 us; speedup 1.0000x reference)
//
#include <hip/hip_runtime.h>

typedef unsigned short u16;
typedef __bf16  bfrag  __attribute__((ext_vector_type(8)));   // MFMA A/B operand (4 VGPRs)
typedef float   f32x4  __attribute__((ext_vector_type(4)));   // MFMA C/D operand
typedef u16     u16x8  __attribute__((ext_vector_type(8)));
typedef u16     u16x4  __attribute__((ext_vector_type(4)));

__device__ __forceinline__ float bf2f(u16 u) {
    unsigned v = ((unsigned)u) << 16;
    return __builtin_bit_cast(float, v);
}
__device__ __forceinline__ u16 f2bf(float f) {   // round-to-nearest-even
    unsigned x = __builtin_bit_cast(unsigned, f);
    unsigned r = (x + 0x7fffu + ((x >> 16) & 1u)) >> 16;
    return (u16)r;
}
__device__ __forceinline__ void g2l16(const u16* g, u16* l) {
    // 16B per lane -> lds_base + lane*16 (wave-uniform LDS base)
    __builtin_amdgcn_global_load_lds((__attribute__((address_space(1))) void*)g,
                                     (__attribute__((address_space(3))) void*)l, 16, 0, 0);
}
__device__ __forceinline__ float gelu_tanh(float x) {
    // 0.5x(1+tanh(c)) == x * sigmoid(2c)
    float c = 1.5957691216057308f * (x + 0.044715f * x * x * x);
    return x * __frcp_rn(1.0f + __expf(-c));
}

// BK=64 LDS tiles: row = 128 B = 8 chunks of 16 B = exactly one 32-bank stripe.
// Swizzle phys_chunk = logical_chunk ^ (row & 7): conflict-free frag reads.
#define SW64(l)   (((((l) & 7) ^ (((l) >> 3) & 7))) * 8)
#define RS64(kk, quad, l15)  (((((kk) * 4 + (quad)) ^ ((l15) & 7))) * 8)

// ---------------- weight transposes + LN1 fused in ONE kernel ---------------
// v2: 64x64 fp32 tiles; transpose via padded LDS; each thread WRITES 16
// contiguous bf16 (2 x 16B stores) -> full store coalescing (old version
// stored 2B/lane). Grid: 4096 transpose tiles + 4096 LN rows.
__global__ __launch_bounds__(256) void wtln(
        const float* __restrict__ Wq, const float* __restrict__ Wk,
        const float* __restrict__ Wv, const float* __restrict__ Wo,
        const float* __restrict__ W1, const float* __restrict__ W2,
        const float* __restrict__ W3,
        u16* __restrict__ WqkvT, u16* __restrict__ WoT,
        u16* __restrict__ W12T, u16* __restrict__ W3T,
        const float* __restrict__ x, const float* __restrict__ ln1_s,
        const float* __restrict__ ln1_b, u16* __restrict__ xn1) {
    __shared__ float tile[64][65];
    int blk = blockIdx.x;
    if (blk >= 4096) {
        int row = blk - 4096, t = threadIdx.x;
        float4 v = ((const float4*)(x + (size_t)row * 1024))[t];
        float sum = v.x + v.y + v.z + v.w;
        float sq  = v.x * v.x + v.y * v.y + v.z * v.z + v.w * v.w;
#pragma unroll
        for (int off = 1; off < 64; off <<= 1) {
            sum += __shfl_xor(sum, off);
            sq  += __shfl_xor(sq,  off);
        }
        float* s1 = &tile[0][0];
        float* s2 = &tile[0][8];
        int wave = t >> 6;
        if ((t & 63) == 0) { s1[wave] = sum; s2[wave] = sq; }
        __syncthreads();
        sum = s1[0] + s1[1] + s1[2] + s1[3];
        sq  = s2[0] + s2[1] + s2[2] + s2[3];
        float mean = sum * (1.0f / 1024.0f);
        float var  = sq  * (1.0f / 1024.0f) - mean * mean;
        float inv  = rsqrtf(var + 1e-6f);
        float4 sc = ((const float4*)ln1_s)[t], bb = ((const float4*)ln1_b)[t];
        u16x4 o;
        o[0] = f2bf((v.x - mean) * inv * sc.x + bb.x);
        o[1] = f2bf((v.y - mean) * inv * sc.y + bb.y);
        o[2] = f2bf((v.z - mean) * inv * sc.z + bb.z);
        o[3] = f2bf((v.w - mean) * inv * sc.w + bb.w);
        *(u16x4*)&xn1[(size_t)row * 1024 + t * 4] = o;
        return;
    }
    const float* W; u16* Wt; int R, C, local;
    if (blk < 768) {
        int w = blk >> 8; local = blk & 255;
        W = (w == 0) ? Wq : (w == 1) ? Wk : Wv;
        Wt = WqkvT + (size_t)w * 1024 * 1024; R = 1024; C = 1024;
    } else if (blk < 1024) { W = Wo; Wt = WoT; R = 1024; C = 1024; local = blk - 768; }
    else if (blk < 2048)   { W = W1; Wt = W12T; R = 1024; C = 4096; local = blk - 1024; }
    else if (blk < 3072)   { W = W2; Wt = W12T + (size_t)4096 * 1024; R = 1024; C = 4096; local = blk - 2048; }
    else                   { W = W3; Wt = W3T; R = 4096; C = 1024; local = blk - 3072; }
    int tiles_x = C >> 6;
    int c0 = (local % tiles_x) * 64, r0 = (local / tiles_x) * 64;
    int t = threadIdx.x;
    int lr = t >> 4, lc = (t & 15) * 4;
#pragma unroll
    for (int p = 0; p < 4; p++) {
        float4 v = *(const float4*)&W[(size_t)(r0 + p * 16 + lr) * C + c0 + lc];
        *(float4*)&tile[p * 16 + lr][lc] = v;
    }
    __syncthreads();
    int oc = t >> 2;            // output row = source col (0..63)
    int rs = (t & 3) * 16;      // 16-wide r segment
    u16x8 o0, o1;
#pragma unroll
    for (int j = 0; j < 8; j++) o0[j] = f2bf(tile[rs + j][oc]);
#pragma unroll
    for (int j = 0; j < 8; j++) o1[j] = f2bf(tile[rs + 8 + j][oc]);
    u16* dst = &Wt[(size_t)(c0 + oc) * R + r0 + rs];
    *(u16x8*)dst       = o0;
    *(u16x8*)(dst + 8) = o1;
}

// ---- gemm64: 4-wave 128x128 block tile, 64x64 wave tile, BK=64 -------------
// EPI 0: bf16 partial store to o[kz] (split-K) | 4: QKV + per-head LN.
template <int EPI>
__global__ __launch_bounds__(256, 3) void gemm64(const u16* __restrict__ A,
                                                 const u16* __restrict__ Bt,
                                                 const float* __restrict__ bias,
                                                 const float* __restrict__ bias2,
                                                 const float* __restrict__ bias3,
                                                 const float* __restrict__ qn_s,
                                                 const float* __restrict__ qn_b,
                                                 const float* __restrict__ kn_s,
                                                 const float* __restrict__ kn_b,
                                                 u16* __restrict__ o0,
                                                 u16* __restrict__ o1,
                                                 u16* __restrict__ o2,
                                                 u16* __restrict__ o3,
                                                 int M, int N, int K, int Klen) {
    __shared__ u16 As[128 * 64];
    __shared__ u16 Bs[128 * 64];
    int tid = threadIdx.x, wave = tid >> 6, lane = tid & 63;
    int quad = lane >> 4, l15 = lane & 15;
    int row0 = blockIdx.y * 128, col0 = blockIdx.x * 128;
    int kz = blockIdx.z;
    int wr = (wave >> 1) * 64, wc = (wave & 1) * 64;
    int swz = SW64(lane);

    f32x4 acc[4][4] = {};

    const u16* gA = A  + (size_t)(row0 + wave * 32 + (lane >> 3)) * K + kz * Klen + swz;
    const u16* gB = Bt + (size_t)(col0 + wave * 32 + (lane >> 3)) * K + kz * Klen + swz;
    u16* lA = &As[wave * 32 * 64];
    u16* lB = &Bs[wave * 32 * 64];

    for (int k0 = 0; k0 < Klen; k0 += 64) {
        __syncthreads();
#pragma unroll
        for (int j = 0; j < 4; j++) {
            g2l16(gA + k0 + j * 8 * K, lA + j * 8 * 64);
            g2l16(gB + k0 + j * 8 * K, lB + j * 8 * 64);
        }
        __syncthreads();
#pragma unroll
        for (int kk = 0; kk < 2; kk++) {
            int rs = RS64(kk, quad, l15);
            bfrag af[4], bf[4];
#pragma unroll
            for (int mi = 0; mi < 4; mi++)
                af[mi] = *(const bfrag*)&As[(wr + mi * 16 + l15) * 64 + rs];
#pragma unroll
            for (int ni = 0; ni < 4; ni++)
                bf[ni] = *(const bfrag*)&Bs[(wc + ni * 16 + l15) * 64 + rs];
#pragma unroll
            for (int mi = 0; mi < 4; mi++)
#pragma unroll
                for (int ni = 0; ni < 4; ni++)
                    acc[mi][ni] = __builtin_amdgcn_mfma_f32_16x16x32_bf16(
                        af[mi], bf[ni], acc[mi][ni], 0, 0, 0);
        }
    }

    if (EPI == 0) {
        u16* P = (kz == 0) ? o0 : (kz == 1) ? o1 : (kz == 2) ? o2 : o3;
#pragma unroll
        for (int mi = 0; mi < 4; mi++) {
            int rbase = row0 + wr + mi * 16 + quad * 4;
#pragma unroll
            for (int r = 0; r < 4; r++)
#pragma unroll
                for (int ni = 0; ni < 4; ni++)
                    P[(size_t)(rbase + r) * N + col0 + wc + ni * 16 + l15] =
                        f2bf(acc[mi][ni][r]);
        }
    } else {
        int cbase = col0 + wc;
        int z = cbase >> 10;              // 0=q, 1=k, 2=v
        int hd = (cbase >> 6) & 15;
        const float* bp = (z == 0) ? bias : (z == 1) ? bias2 : bias3;
        float post = (z == 0) ? 0.125f : 1.0f;
        float bv[4], sn[4], bn[4];
#pragma unroll
        for (int ni = 0; ni < 4; ni++)
            bv[ni] = bp[(cbase & 1023) + ni * 16 + l15];
        if (z < 2) {
            const float* ns = (z == 0) ? qn_s : kn_s;
            const float* nb = (z == 0) ? qn_b : kn_b;
#pragma unroll
            for (int ni = 0; ni < 4; ni++) {
                sn[ni] = ns[hd * 64 + ni * 16 + l15];
                bn[ni] = nb[hd * 64 + ni * 16 + l15];
            }
        }
#pragma unroll
        for (int mi = 0; mi < 4; mi++) {
            int rbase = row0 + wr + mi * 16 + quad * 4;
#pragma unroll
            for (int r = 0; r < 4; r++) {
                float v0 = acc[mi][0][r] + bv[0];
                float v1 = acc[mi][1][r] + bv[1];
                float v2 = acc[mi][2][r] + bv[2];
                float v3 = acc[mi][3][r] + bv[3];
                size_t rb = (size_t)(rbase + r) * N + cbase;
                if (z == 2) {
                    o0[rb + 0 * 16 + l15] = f2bf(v0);
                    o0[rb + 1 * 16 + l15] = f2bf(v1);
                    o0[rb + 2 * 16 + l15] = f2bf(v2);
                    o0[rb + 3 * 16 + l15] = f2bf(v3);
                } else {
                    float s  = v0 + v1 + v2 + v3;
                    float sq = v0 * v0 + v1 * v1 + v2 * v2 + v3 * v3;
#pragma unroll
                    for (int m = 1; m < 16; m <<= 1) {
                        s  += __shfl_xor(s,  m);
                        sq += __shfl_xor(sq, m);
                    }
                    float mean = s * (1.0f / 64.0f);
                    float var  = sq * (1.0f / 64.0f) - mean * mean;
                    float inv  = rsqrtf(var + 1e-6f);
                    o0[rb + 0 * 16 + l15] = f2bf(((v0 - mean) * inv * sn[0] + bn[0]) * post);
                    o0[rb + 1 * 16 + l15] = f2bf(((v1 - mean) * inv * sn[1] + bn[1]) * post);
                    o0[rb + 2 * 16 + l15] = f2bf(((v2 - mean) * inv * sn[2] + bn[2]) * post);
                    o0[rb + 3 * 16 + l15] = f2bf(((v3 - mean) * inv * sn[3] + bn[3]) * post);
                }
            }
        }
    }
}

// ---------------- fused GeGLU FFN GEMM, BK=64 (R0-proven form) --------------
__global__ __launch_bounds__(256, 2) void gemm_w12(const u16* __restrict__ A,
                                                   const u16* __restrict__ W12T,
                                                   const float* __restrict__ b1,
                                                   const float* __restrict__ b2,
                                                   u16* __restrict__ H) {
    __shared__ u16 As[128 * 64];
    __shared__ u16 B1s[128 * 64];
    __shared__ u16 B2s[128 * 64];
    int tid = threadIdx.x, wave = tid >> 6, lane = tid & 63;
    int quad = lane >> 4, l15 = lane & 15;
    int row0 = blockIdx.y * 128, col0 = blockIdx.x * 128;
    int wr = (wave >> 1) * 64, wc = (wave & 1) * 64;
    int swz = SW64(lane);

    f32x4 acc1[4][4] = {}, acc2[4][4] = {};

    const u16* gA  = A    + (size_t)(row0 + wave * 32 + (lane >> 3)) * 1024 + swz;
    const u16* gB1 = W12T + (size_t)(col0 + wave * 32 + (lane >> 3)) * 1024 + swz;
    const u16* gB2 = gB1  + (size_t)4096 * 1024;
    u16* lA  = &As [wave * 32 * 64];
    u16* lB1 = &B1s[wave * 32 * 64];
    u16* lB2 = &B2s[wave * 32 * 64];

    for (int k0 = 0; k0 < 1024; k0 += 64) {
        __syncthreads();
#pragma unroll
        for (int j = 0; j < 4; j++) {
            g2l16(gA  + k0 + j * 8 * 1024, lA  + j * 8 * 64);
            g2l16(gB1 + k0 + j * 8 * 1024, lB1 + j * 8 * 64);
            g2l16(gB2 + k0 + j * 8 * 1024, lB2 + j * 8 * 64);
        }
        __syncthreads();
#pragma unroll
        for (int kk = 0; kk < 2; kk++) {
            int rs = RS64(kk, quad, l15);
            bfrag af[4], b1f[4], b2f[4];
#pragma unroll
            for (int mi = 0; mi < 4; mi++)
                af[mi] = *(const bfrag*)&As[(wr + mi * 16 + l15) * 64 + rs];
#pragma unroll
            for (int ni = 0; ni < 4; ni++) {
                b1f[ni] = *(const bfrag*)&B1s[(wc + ni * 16 + l15) * 64 + rs];
                b2f[ni] = *(const bfrag*)&B2s[(wc + ni * 16 + l15) * 64 + rs];
            }
#pragma unroll
            for (int mi = 0; mi < 4; mi++)
#pragma unroll
                for (int ni = 0; ni < 4; ni++) {
                    acc1[mi][ni] = __builtin_amdgcn_mfma_f32_16x16x32_bf16(
                        af[mi], b1f[ni], acc1[mi][ni], 0, 0, 0);
                    acc2[mi][ni] = __builtin_amdgcn_mfma_f32_16x16x32_bf16(
                        af[mi], b2f[ni], acc2[mi][ni], 0, 0, 0);
                }
        }
    }

    float bv1[4], bv2[4];
    int cols[4];
#pragma unroll
    for (int ni = 0; ni < 4; ni++) {
        cols[ni] = col0 + wc + ni * 16 + l15;
        bv1[ni] = b1[cols[ni]];
        bv2[ni] = b2[cols[ni]];
    }
#pragma unroll
    for (int mi = 0; mi < 4; mi++) {
        int rbase = row0 + wr + mi * 16 + quad * 4;
#pragma unroll
        for (int r = 0; r < 4; r++) {
#pragma unroll
            for (int ni = 0; ni < 4; ni++) {
                float x1 = acc1[mi][ni][r] + bv1[ni];
                float x2 = acc2[mi][ni][r] + bv2[ni];
                H[(size_t)(rbase + r) * 4096 + cols[ni]] = f2bf(x1 * gelu_tanh(x2));
            }
        }
    }
}

// ---- fused Wo-reduce + residual + LN2 --------------------------------------
__global__ __launch_bounds__(256) void reduce_ln(const u16* __restrict__ p0,
                                                 const u16* __restrict__ p1,
                                                 const float* __restrict__ x,
                                                 const float* __restrict__ bo,
                                                 const float* __restrict__ s,
                                                 const float* __restrict__ b,
                                                 float* __restrict__ xmid,
                                                 u16* __restrict__ xn2) {
    int row = blockIdx.x, t = threadIdx.x;
    size_t i = (size_t)row * 1024 + t * 4;
    float4 xv = *(const float4*)&x[i];
    float4 bb = *(const float4*)&bo[t * 4];
    u16x4 a0 = *(const u16x4*)&p0[i];
    u16x4 a1 = *(const u16x4*)&p1[i];
    float4 v;
    v.x = xv.x + bb.x + bf2f(a0[0]) + bf2f(a1[0]);
    v.y = xv.y + bb.y + bf2f(a0[1]) + bf2f(a1[1]);
    v.z = xv.z + bb.z + bf2f(a0[2]) + bf2f(a1[2]);
    v.w = xv.w + bb.w + bf2f(a0[3]) + bf2f(a1[3]);
    *(float4*)&xmid[i] = v;
    float sum = v.x + v.y + v.z + v.w;
    float sq  = v.x * v.x + v.y * v.y + v.z * v.z + v.w * v.w;
#pragma unroll
    for (int off = 1; off < 64; off <<= 1) {
        sum += __shfl_xor(sum, off);
        sq  += __shfl_xor(sq,  off);
    }
    __shared__ float s1[4], s2[4];
    int wave = t >> 6;
    if ((t & 63) == 0) { s1[wave] = sum; s2[wave] = sq; }
    __syncthreads();
    sum = s1[0] + s1[1] + s1[2] + s1[3];
    sq  = s2[0] + s2[1] + s2[2] + s2[3];
    float mean = sum * (1.0f / 1024.0f);
    float var  = sq  * (1.0f / 1024.0f) - mean * mean;
    float inv  = rsqrtf(var + 1e-6f);
    float4 sc = ((const float4*)s)[t], lb = ((const float4*)b)[t];
    u16x4 o;
    o[0] = f2bf((v.x - mean) * inv * sc.x + lb.x);
    o[1] = f2bf((v.y - mean) * inv * sc.y + lb.y);
    o[2] = f2bf((v.z - mean) * inv * sc.z + lb.z);
    o[3] = f2bf((v.w - mean) * inv * sc.w + lb.w);
    *(u16x4*)&xn2[i] = o;
}

// ---------------- reduce: out = xmid + b3 + sum of 4 bf16 partials ----------
__global__ __launch_bounds__(256) void reduce4(const u16* __restrict__ p0,
                                               const u16* __restrict__ p1,
                                               const u16* __restrict__ p2,
                                               const u16* __restrict__ p3,
                                               const float* __restrict__ xmid,
                                               const float* __restrict__ b3,
                                               float* __restrict__ out) {
    size_t i = ((size_t)blockIdx.x * 256 + threadIdx.x) * 4;
    float4 xm = *(const float4*)&xmid[i];
    float4 bb = *(const float4*)&b3[i & 1023];
    u16x4 a0 = *(const u16x4*)&p0[i];
    u16x4 a1 = *(const u16x4*)&p1[i];
    u16x4 a2 = *(const u16x4*)&p2[i];
    u16x4 a3 = *(const u16x4*)&p3[i];
    float4 o;
    o.x = xm.x + bb.x + bf2f(a0[0]) + bf2f(a1[0]) + bf2f(a2[0]) + bf2f(a3[0]);
    o.y = xm.y + bb.y + bf2f(a0[1]) + bf2f(a1[1]) + bf2f(a2[1]) + bf2f(a3[1]);
    o.z = xm.z + bb.z + bf2f(a0[2]) + bf2f(a1[2]) + bf2f(a2[2]) + bf2f(a3[2]);
    o.w = xm.w + bb.w + bf2f(a0[3]) + bf2f(a1[3]) + bf2f(a2[3]) + bf2f(a3[3]);
    *(float4*)&out[i] = o;
}

// ---------------- Flash attention v2 ----------------------------------------
// grid (16 qt, 16 h, 4 b); 256 threads; 64-row Q tiles (16 rows/wave).
// Q frags AND K frags direct from global (K rows are token-major = exactly
// B-fragment shaped, 128B/row; K/V per (b,h) = 256 KB, L2-resident across the
// 16 qt blocks -> staging K through LDS was pure overhead, catalog lesson #7).
// K loads hoisted above V ds_writes so L2 latency hides under staging+barrier.
// No-max softmax (|s|<=8 by QK-norm); lane-local l partials. Vt staged
// seg=wave/key=lane (must stage: d-strided in global). Ps stride 68 u16.
#define LPV 72
#define LPP 68
__global__ __launch_bounds__(256, 4) void flash(const u16* __restrict__ qkv,
                                                u16* __restrict__ o) {
    int qt = blockIdx.x, h = blockIdx.y, b = blockIdx.z;
    int tid = threadIdx.x, wave = tid >> 6, lane = tid & 63;
    int quad = lane >> 4, l15 = lane & 15;

    __shared__ u16 Vt[64 * LPV];   // [d][key]
    __shared__ u16 Ps[64 * LPP];

    // Q A-fragments straight from global (rows wave*16+l15, 16B contiguous)
    const u16* qrow = qkv + (size_t)(b * 1024 + qt * 64 + wave * 16 + l15) * 3072
                      + h * 64 + quad * 8;
    bfrag aq0 = *(const bfrag*)qrow;
    bfrag aq1 = *(const bfrag*)(qrow + 32);

    f32x4 accO[4] = {};
    float l_run[4] = {0.f, 0.f, 0.f, 0.f};

    for (int kt = 0; kt < 16; kt++) {
        __syncthreads();   // Vt safe to overwrite (prev PV reads done)
        // V loads (will be transposed into LDS)
        const u16* vsrc = qkv + (size_t)(b * 1024 + kt * 64 + lane) * 3072
                          + 2048 + h * 64 + wave * 16;
        u16x8 v0 = *(const u16x8*)vsrc, v1 = *(const u16x8*)(vsrc + 8);
        // K B-fragments direct from global (no LDS) — issue before ds_writes
        bfrag bk[4][2];
        const u16* kbase = qkv + (size_t)(b * 1024 + kt * 64) * 3072
                           + 1024 + h * 64;
#pragma unroll
        for (int ct = 0; ct < 4; ct++) {
            const u16* kr = kbase + (size_t)(ct * 16 + l15) * 3072 + quad * 8;
            bk[ct][0] = *(const bfrag*)kr;
            bk[ct][1] = *(const bfrag*)(kr + 32);
        }
        // V transposed into LDS: seg = wave, key = lane
#pragma unroll
        for (int j = 0; j < 8; j++) Vt[(wave * 16 + j) * LPV + lane]     = v0[j];
#pragma unroll
        for (int j = 0; j < 8; j++) Vt[(wave * 16 + 8 + j) * LPV + lane] = v1[j];
        __syncthreads();

        // S = Q x K^T over 64 keys
        f32x4 accS[4] = {};
#pragma unroll
        for (int ct = 0; ct < 4; ct++) {
            accS[ct] = __builtin_amdgcn_mfma_f32_16x16x32_bf16(aq0, bk[ct][0], accS[ct], 0, 0, 0);
            accS[ct] = __builtin_amdgcn_mfma_f32_16x16x32_bf16(aq1, bk[ct][1], accS[ct], 0, 0, 0);
        }

        // p = exp(s) (no max needed), lane-local l partial, write P
#pragma unroll
        for (int r = 0; r < 4; r++) {
            float p0 = __expf(accS[0][r]);
            float p1 = __expf(accS[1][r]);
            float p2 = __expf(accS[2][r]);
            float p3 = __expf(accS[3][r]);
            l_run[r] += (p0 + p1) + (p2 + p3);
            int pbase = (wave * 16 + quad * 4 + r) * LPP + l15;
            Ps[pbase + 0]  = f2bf(p0);
            Ps[pbase + 16] = f2bf(p1);
            Ps[pbase + 32] = f2bf(p2);
            Ps[pbase + 48] = f2bf(p3);
        }

        // O += P x V  (ap via two b64 reads; Vt rows give b128 B-frags)
#pragma unroll
        for (int kk = 0; kk < 2; kk++) {
            const u16* pp = &Ps[(wave * 16 + l15) * LPP + kk * 32 + quad * 8];
            u16x4 lo = *(const u16x4*)pp;
            u16x4 hi = *(const u16x4*)(pp + 4);
            u16x8 apu;
            apu[0] = lo[0]; apu[1] = lo[1]; apu[2] = lo[2]; apu[3] = lo[3];
            apu[4] = hi[0]; apu[5] = hi[1]; apu[6] = hi[2]; apu[7] = hi[3];
            bfrag ap = __builtin_bit_cast(bfrag, apu);
#pragma unroll
            for (int oc = 0; oc < 4; oc++) {
                bfrag bv = *(const bfrag*)&Vt[(oc * 16 + l15) * LPV + kk * 32 + quad * 8];
                accO[oc] = __builtin_amdgcn_mfma_f32_16x16x32_bf16(ap, bv, accO[oc], 0, 0, 0);
            }
        }
    }

    // epilogue: reduce l over the 16 row-lanes, normalize, store
#pragma unroll
    for (int r = 0; r < 4; r++) {
        float l = l_run[r];
#pragma unroll
        for (int m = 1; m < 16; m <<= 1) l += __shfl_xor(l, m);
        float linv = 1.0f / l;
        int srow = qt * 64 + wave * 16 + quad * 4 + r;
#pragma unroll
        for (int oc = 0; oc < 4; oc++)
            o[(size_t)(b * 1024 + srow) * 1024 + h * 64 + oc * 16 + l15] =
                f2bf(accO[oc][r] * linv);
    }
}

// ---------------------------------------------------------------------------
extern "C" void kernel_launch(void* const* d_in, const int* in_sizes, int n_in,
                              void* d_out, int out_size, void* d_ws, size_t ws_size,
                              hipStream_t stream) {
    const float* x     = (const float*)d_in[0];
    const float* ln1_s = (const float*)d_in[2];
    const float* ln1_b = (const float*)d_in[3];
    const float* Wq = (const float*)d_in[4];  const float* bq = (const float*)d_in[5];
    const float* Wk = (const float*)d_in[6];  const float* bk = (const float*)d_in[7];
    const float* Wv = (const float*)d_in[8];  const float* bv = (const float*)d_in[9];
    const float* qn_s = (const float*)d_in[10]; const float* qn_b = (const float*)d_in[11];
    const float* kn_s = (const float*)d_in[12]; const float* kn_b = (const float*)d_in[13];
    const float* Wo = (const float*)d_in[14]; const float* bo = (const float*)d_in[15];
    const float* ln2_s = (const float*)d_in[16]; const float* ln2_b = (const float*)d_in[17];
    const float* W1 = (const float*)d_in[18]; const float* b1 = (const float*)d_in[19];
    const float* W2 = (const float*)d_in[20]; const float* b2 = (const float*)d_in[21];
    const float* W3 = (const float*)d_in[22]; const float* b3 = (const float*)d_in[23];
    float* out = (float*)d_out;

    char* ws = (char*)d_ws;
    const size_t MB = (size_t)1 << 20;
    u16* WqkvT = (u16*)(ws + 0);         // 0..6    dead after QKV; then p0 @0
    u16* WoT   = (u16*)(ws + 6 * MB);    // 6..8    dead after Wo
    u16* W12T  = (u16*)(ws + 8 * MB);    // 8..24   dead after W12; then p1/p2
    u16* W3T   = (u16*)(ws + 24 * MB);   // 24..32  dead after splitk
    u16* xn1   = (u16*)(ws + 32 * MB);   // 32..40  dead after QKV
    u16* attn  = (u16*)(ws + 32 * MB);   //   reuse: dead after Wo-gemm
    u16* xn2   = (u16*)(ws + 32 * MB);   //   reuse: dead after W12
    u16* qkv   = (u16*)(ws + 40 * MB);   // 40..64  dead after flash
    float* xmid = (float*)(ws + 40 * MB);//   reuse: 40..56, alive until reduce4
    u16* p3    = (u16*)(ws + 56 * MB);   // 56..64
    u16* h     = (u16*)(ws + 64 * MB);   // 64..96  dead after splitk
    u16* wp0   = (u16*)(ws + 64 * MB);   // Wo partials: 64..72, 72..80
    u16* wp1   = (u16*)(ws + 72 * MB);   //   dead after reduce_ln (before h)
    u16* p0    = (u16*)(ws + 0);
    u16* p1    = (u16*)(ws + 8 * MB);
    u16* p2    = (u16*)(ws + 16 * MB);
    // peak = 96 MB

    wtln<<<8192, 256, 0, stream>>>(Wq, Wk, Wv, Wo, W1, W2, W3,
                                   WqkvT, WoT, W12T, W3T,
                                   x, ln1_s, ln1_b, xn1);

    // fused QKV + per-head QK-norm (BK=64)
    gemm64<4><<<dim3(24, 32, 1), 256, 0, stream>>>(
        xn1, WqkvT, bq, bk, bv, qn_s, qn_b, kn_s, kn_b,
        qkv, nullptr, nullptr, nullptr, 4096, 3072, 1024, 1024);

    flash<<<dim3(16, 16, 4), 256, 0, stream>>>(qkv, attn);

    // Wo split-K=2 partials (BK=64)
    gemm64<0><<<dim3(8, 32, 2), 256, 0, stream>>>(
        attn, WoT, nullptr, nullptr, nullptr, nullptr, nullptr, nullptr, nullptr,
        wp0, wp1, nullptr, nullptr, 4096, 1024, 1024, 512);

    // xmid = x + bo + wp0 + wp1; xn2 = LN2(xmid)
    reduce_ln<<<4096, 256, 0, stream>>>(wp0, wp1, x, bo, ln2_s, ln2_b, xmid, xn2);

    // fused GeGLU FFN (BK=64)
    gemm_w12<<<dim3(32, 32), 256, 0, stream>>>(xn2, W12T, b1, b2, h);

    // W3 split-K=4 partials (BK=64)
    gemm64<0><<<dim3(8, 32, 4), 256, 0, stream>>>(
        h, W3T, nullptr, nullptr, nullptr, nullptr, nullptr, nullptr, nullptr,
        p0, p1, p2, p3, 4096, 1024, 4096, 1024);

    // out = xmid + b3 + sum(partials)
    reduce4<<<4096, 256, 0, stream>>>(p0, p1, p2, p3, xmid, b3, out);
}

// Round 6
// 398.059 us; speedup vs baseline: 1.1214x; 1.1214x over previous
//
#include <hip/hip_runtime.h>

typedef unsigned short u16;
typedef __bf16  bfrag  __attribute__((ext_vector_type(8)));   // MFMA A/B operand (4 VGPRs)
typedef float   f32x4  __attribute__((ext_vector_type(4)));   // MFMA C/D operand
typedef u16     u16x8  __attribute__((ext_vector_type(8)));
typedef u16     u16x4  __attribute__((ext_vector_type(4)));

__device__ __forceinline__ float bf2f(u16 u) {
    unsigned v = ((unsigned)u) << 16;
    return __builtin_bit_cast(float, v);
}
__device__ __forceinline__ u16 f2bf(float f) {   // round-to-nearest-even
    unsigned x = __builtin_bit_cast(unsigned, f);
    unsigned r = (x + 0x7fffu + ((x >> 16) & 1u)) >> 16;
    return (u16)r;
}
__device__ __forceinline__ void g2l16(const u16* g, u16* l) {
    // 16B per lane -> lds_base + lane*16 (wave-uniform LDS base)
    __builtin_amdgcn_global_load_lds((__attribute__((address_space(1))) void*)g,
                                     (__attribute__((address_space(3))) void*)l, 16, 0, 0);
}
__device__ __forceinline__ float gelu_tanh(float x) {
    // 0.5x(1+tanh(c)) == x * sigmoid(2c)
    float c = 1.5957691216057308f * (x + 0.044715f * x * x * x);
    return x * __frcp_rn(1.0f + __expf(-c));
}

// BK=64 LDS tiles: row = 128 B = 8 chunks of 16 B = exactly one 32-bank stripe.
// Swizzle phys_chunk = logical_chunk ^ (row & 7): conflict-free frag reads.
#define SW64(l)   (((((l) & 7) ^ (((l) >> 3) & 7))) * 8)
#define RS64(kk, quad, l15)  (((((kk) * 4 + (quad)) ^ ((l15) & 7))) * 8)

// ---------------- weight transposes + LN1 fused in ONE kernel ---------------
// 64x64 fp32 tiles; transpose via padded LDS; each thread WRITES 16
// contiguous bf16 (2 x 16B stores) -> full store coalescing.
__global__ __launch_bounds__(256) void wtln(
        const float* __restrict__ Wq, const float* __restrict__ Wk,
        const float* __restrict__ Wv, const float* __restrict__ Wo,
        const float* __restrict__ W1, const float* __restrict__ W2,
        const float* __restrict__ W3,
        u16* __restrict__ WqkvT, u16* __restrict__ WoT,
        u16* __restrict__ W12T, u16* __restrict__ W3T,
        const float* __restrict__ x, const float* __restrict__ ln1_s,
        const float* __restrict__ ln1_b, u16* __restrict__ xn1) {
    __shared__ float tile[64][65];
    int blk = blockIdx.x;
    if (blk >= 4096) {
        int row = blk - 4096, t = threadIdx.x;
        float4 v = ((const float4*)(x + (size_t)row * 1024))[t];
        float sum = v.x + v.y + v.z + v.w;
        float sq  = v.x * v.x + v.y * v.y + v.z * v.z + v.w * v.w;
#pragma unroll
        for (int off = 1; off < 64; off <<= 1) {
            sum += __shfl_xor(sum, off);
            sq  += __shfl_xor(sq,  off);
        }
        float* s1 = &tile[0][0];
        float* s2 = &tile[0][8];
        int wave = t >> 6;
        if ((t & 63) == 0) { s1[wave] = sum; s2[wave] = sq; }
        __syncthreads();
        sum = s1[0] + s1[1] + s1[2] + s1[3];
        sq  = s2[0] + s2[1] + s2[2] + s2[3];
        float mean = sum * (1.0f / 1024.0f);
        float var  = sq  * (1.0f / 1024.0f) - mean * mean;
        float inv  = rsqrtf(var + 1e-6f);
        float4 sc = ((const float4*)ln1_s)[t], bb = ((const float4*)ln1_b)[t];
        u16x4 o;
        o[0] = f2bf((v.x - mean) * inv * sc.x + bb.x);
        o[1] = f2bf((v.y - mean) * inv * sc.y + bb.y);
        o[2] = f2bf((v.z - mean) * inv * sc.z + bb.z);
        o[3] = f2bf((v.w - mean) * inv * sc.w + bb.w);
        *(u16x4*)&xn1[(size_t)row * 1024 + t * 4] = o;
        return;
    }
    const float* W; u16* Wt; int R, C, local;
    if (blk < 768) {
        int w = blk >> 8; local = blk & 255;
        W = (w == 0) ? Wq : (w == 1) ? Wk : Wv;
        Wt = WqkvT + (size_t)w * 1024 * 1024; R = 1024; C = 1024;
    } else if (blk < 1024) { W = Wo; Wt = WoT; R = 1024; C = 1024; local = blk - 768; }
    else if (blk < 2048)   { W = W1; Wt = W12T; R = 1024; C = 4096; local = blk - 1024; }
    else if (blk < 3072)   { W = W2; Wt = W12T + (size_t)4096 * 1024; R = 1024; C = 4096; local = blk - 2048; }
    else                   { W = W3; Wt = W3T; R = 4096; C = 1024; local = blk - 3072; }
    int tiles_x = C >> 6;
    int c0 = (local % tiles_x) * 64, r0 = (local / tiles_x) * 64;
    int t = threadIdx.x;
    int lr = t >> 4, lc = (t & 15) * 4;
#pragma unroll
    for (int p = 0; p < 4; p++) {
        float4 v = *(const float4*)&W[(size_t)(r0 + p * 16 + lr) * C + c0 + lc];
        *(float4*)&tile[p * 16 + lr][lc] = v;
    }
    __syncthreads();
    int oc = t >> 2;            // output row = source col (0..63)
    int rs = (t & 3) * 16;      // 16-wide r segment
    u16x8 o0, o1;
#pragma unroll
    for (int j = 0; j < 8; j++) o0[j] = f2bf(tile[rs + j][oc]);
#pragma unroll
    for (int j = 0; j < 8; j++) o1[j] = f2bf(tile[rs + 8 + j][oc]);
    u16* dst = &Wt[(size_t)(c0 + oc) * R + r0 + rs];
    *(u16x8*)dst       = o0;
    *(u16x8*)(dst + 8) = o1;
}

// ---- gemm64: 4-wave 128x128 block tile, 64x64 wave tile, BK=64 -------------
// EPI 0: bf16 partial store to o[kz] (split-K) | 4: QKV + per-head LN.
template <int EPI>
__global__ __launch_bounds__(256, 3) void gemm64(const u16* __restrict__ A,
                                                 const u16* __restrict__ Bt,
                                                 const float* __restrict__ bias,
                                                 const float* __restrict__ bias2,
                                                 const float* __restrict__ bias3,
                                                 const float* __restrict__ qn_s,
                                                 const float* __restrict__ qn_b,
                                                 const float* __restrict__ kn_s,
                                                 const float* __restrict__ kn_b,
                                                 u16* __restrict__ o0,
                                                 u16* __restrict__ o1,
                                                 u16* __restrict__ o2,
                                                 u16* __restrict__ o3,
                                                 int M, int N, int K, int Klen) {
    __shared__ u16 As[128 * 64];
    __shared__ u16 Bs[128 * 64];
    int tid = threadIdx.x, wave = tid >> 6, lane = tid & 63;
    int quad = lane >> 4, l15 = lane & 15;
    int row0 = blockIdx.y * 128, col0 = blockIdx.x * 128;
    int kz = blockIdx.z;
    int wr = (wave >> 1) * 64, wc = (wave & 1) * 64;
    int swz = SW64(lane);

    f32x4 acc[4][4] = {};

    const u16* gA = A  + (size_t)(row0 + wave * 32 + (lane >> 3)) * K + kz * Klen + swz;
    const u16* gB = Bt + (size_t)(col0 + wave * 32 + (lane >> 3)) * K + kz * Klen + swz;
    u16* lA = &As[wave * 32 * 64];
    u16* lB = &Bs[wave * 32 * 64];

    for (int k0 = 0; k0 < Klen; k0 += 64) {
        __syncthreads();
#pragma unroll
        for (int j = 0; j < 4; j++) {
            g2l16(gA + k0 + j * 8 * K, lA + j * 8 * 64);
            g2l16(gB + k0 + j * 8 * K, lB + j * 8 * 64);
        }
        __syncthreads();
#pragma unroll
        for (int kk = 0; kk < 2; kk++) {
            int rs = RS64(kk, quad, l15);
            bfrag af[4], bf[4];
#pragma unroll
            for (int mi = 0; mi < 4; mi++)
                af[mi] = *(const bfrag*)&As[(wr + mi * 16 + l15) * 64 + rs];
#pragma unroll
            for (int ni = 0; ni < 4; ni++)
                bf[ni] = *(const bfrag*)&Bs[(wc + ni * 16 + l15) * 64 + rs];
#pragma unroll
            for (int mi = 0; mi < 4; mi++)
#pragma unroll
                for (int ni = 0; ni < 4; ni++)
                    acc[mi][ni] = __builtin_amdgcn_mfma_f32_16x16x32_bf16(
                        af[mi], bf[ni], acc[mi][ni], 0, 0, 0);
        }
    }

    if (EPI == 0) {
        u16* P = (kz == 0) ? o0 : (kz == 1) ? o1 : (kz == 2) ? o2 : o3;
#pragma unroll
        for (int mi = 0; mi < 4; mi++) {
            int rbase = row0 + wr + mi * 16 + quad * 4;
#pragma unroll
            for (int r = 0; r < 4; r++)
#pragma unroll
                for (int ni = 0; ni < 4; ni++)
                    P[(size_t)(rbase + r) * N + col0 + wc + ni * 16 + l15] =
                        f2bf(acc[mi][ni][r]);
        }
    } else {
        int cbase = col0 + wc;
        int z = cbase >> 10;              // 0=q, 1=k, 2=v
        int hd = (cbase >> 6) & 15;
        const float* bp = (z == 0) ? bias : (z == 1) ? bias2 : bias3;
        float post = (z == 0) ? 0.125f : 1.0f;
        float bv[4], sn[4], bn[4];
#pragma unroll
        for (int ni = 0; ni < 4; ni++)
            bv[ni] = bp[(cbase & 1023) + ni * 16 + l15];
        if (z < 2) {
            const float* ns = (z == 0) ? qn_s : kn_s;
            const float* nb = (z == 0) ? qn_b : kn_b;
#pragma unroll
            for (int ni = 0; ni < 4; ni++) {
                sn[ni] = ns[hd * 64 + ni * 16 + l15];
                bn[ni] = nb[hd * 64 + ni * 16 + l15];
            }
        }
#pragma unroll
        for (int mi = 0; mi < 4; mi++) {
            int rbase = row0 + wr + mi * 16 + quad * 4;
#pragma unroll
            for (int r = 0; r < 4; r++) {
                float v0 = acc[mi][0][r] + bv[0];
                float v1 = acc[mi][1][r] + bv[1];
                float v2 = acc[mi][2][r] + bv[2];
                float v3 = acc[mi][3][r] + bv[3];
                size_t rb = (size_t)(rbase + r) * N + cbase;
                if (z == 2) {
                    o0[rb + 0 * 16 + l15] = f2bf(v0);
                    o0[rb + 1 * 16 + l15] = f2bf(v1);
                    o0[rb + 2 * 16 + l15] = f2bf(v2);
                    o0[rb + 3 * 16 + l15] = f2bf(v3);
                } else {
                    float s  = v0 + v1 + v2 + v3;
                    float sq = v0 * v0 + v1 * v1 + v2 * v2 + v3 * v3;
#pragma unroll
                    for (int m = 1; m < 16; m <<= 1) {
                        s  += __shfl_xor(s,  m);
                        sq += __shfl_xor(sq, m);
                    }
                    float mean = s * (1.0f / 64.0f);
                    float var  = sq * (1.0f / 64.0f) - mean * mean;
                    float inv  = rsqrtf(var + 1e-6f);
                    o0[rb + 0 * 16 + l15] = f2bf(((v0 - mean) * inv * sn[0] + bn[0]) * post);
                    o0[rb + 1 * 16 + l15] = f2bf(((v1 - mean) * inv * sn[1] + bn[1]) * post);
                    o0[rb + 2 * 16 + l15] = f2bf(((v2 - mean) * inv * sn[2] + bn[2]) * post);
                    o0[rb + 3 * 16 + l15] = f2bf(((v3 - mean) * inv * sn[3] + bn[3]) * post);
                }
            }
        }
    }
}

// ---------------- fused GeGLU FFN GEMM, BK=64 (R0-proven form) --------------
__global__ __launch_bounds__(256, 2) void gemm_w12(const u16* __restrict__ A,
                                                   const u16* __restrict__ W12T,
                                                   const float* __restrict__ b1,
                                                   const float* __restrict__ b2,
                                                   u16* __restrict__ H) {
    __shared__ u16 As[128 * 64];
    __shared__ u16 B1s[128 * 64];
    __shared__ u16 B2s[128 * 64];
    int tid = threadIdx.x, wave = tid >> 6, lane = tid & 63;
    int quad = lane >> 4, l15 = lane & 15;
    int row0 = blockIdx.y * 128, col0 = blockIdx.x * 128;
    int wr = (wave >> 1) * 64, wc = (wave & 1) * 64;
    int swz = SW64(lane);

    f32x4 acc1[4][4] = {}, acc2[4][4] = {};

    const u16* gA  = A    + (size_t)(row0 + wave * 32 + (lane >> 3)) * 1024 + swz;
    const u16* gB1 = W12T + (size_t)(col0 + wave * 32 + (lane >> 3)) * 1024 + swz;
    const u16* gB2 = gB1  + (size_t)4096 * 1024;
    u16* lA  = &As [wave * 32 * 64];
    u16* lB1 = &B1s[wave * 32 * 64];
    u16* lB2 = &B2s[wave * 32 * 64];

    for (int k0 = 0; k0 < 1024; k0 += 64) {
        __syncthreads();
#pragma unroll
        for (int j = 0; j < 4; j++) {
            g2l16(gA  + k0 + j * 8 * 1024, lA  + j * 8 * 64);
            g2l16(gB1 + k0 + j * 8 * 1024, lB1 + j * 8 * 64);
            g2l16(gB2 + k0 + j * 8 * 1024, lB2 + j * 8 * 64);
        }
        __syncthreads();
#pragma unroll
        for (int kk = 0; kk < 2; kk++) {
            int rs = RS64(kk, quad, l15);
            bfrag af[4], b1f[4], b2f[4];
#pragma unroll
            for (int mi = 0; mi < 4; mi++)
                af[mi] = *(const bfrag*)&As[(wr + mi * 16 + l15) * 64 + rs];
#pragma unroll
            for (int ni = 0; ni < 4; ni++) {
                b1f[ni] = *(const bfrag*)&B1s[(wc + ni * 16 + l15) * 64 + rs];
                b2f[ni] = *(const bfrag*)&B2s[(wc + ni * 16 + l15) * 64 + rs];
            }
#pragma unroll
            for (int mi = 0; mi < 4; mi++)
#pragma unroll
                for (int ni = 0; ni < 4; ni++) {
                    acc1[mi][ni] = __builtin_amdgcn_mfma_f32_16x16x32_bf16(
                        af[mi], b1f[ni], acc1[mi][ni], 0, 0, 0);
                    acc2[mi][ni] = __builtin_amdgcn_mfma_f32_16x16x32_bf16(
                        af[mi], b2f[ni], acc2[mi][ni], 0, 0, 0);
                }
        }
    }

    float bv1[4], bv2[4];
    int cols[4];
#pragma unroll
    for (int ni = 0; ni < 4; ni++) {
        cols[ni] = col0 + wc + ni * 16 + l15;
        bv1[ni] = b1[cols[ni]];
        bv2[ni] = b2[cols[ni]];
    }
#pragma unroll
    for (int mi = 0; mi < 4; mi++) {
        int rbase = row0 + wr + mi * 16 + quad * 4;
#pragma unroll
        for (int r = 0; r < 4; r++) {
#pragma unroll
            for (int ni = 0; ni < 4; ni++) {
                float x1 = acc1[mi][ni][r] + bv1[ni];
                float x2 = acc2[mi][ni][r] + bv2[ni];
                H[(size_t)(rbase + r) * 4096 + cols[ni]] = f2bf(x1 * gelu_tanh(x2));
            }
        }
    }
}

// ---- fused Wo-reduce + residual + LN2 --------------------------------------
__global__ __launch_bounds__(256) void reduce_ln(const u16* __restrict__ p0,
                                                 const u16* __restrict__ p1,
                                                 const float* __restrict__ x,
                                                 const float* __restrict__ bo,
                                                 const float* __restrict__ s,
                                                 const float* __restrict__ b,
                                                 float* __restrict__ xmid,
                                                 u16* __restrict__ xn2) {
    int row = blockIdx.x, t = threadIdx.x;
    size_t i = (size_t)row * 1024 + t * 4;
    float4 xv = *(const float4*)&x[i];
    float4 bb = *(const float4*)&bo[t * 4];
    u16x4 a0 = *(const u16x4*)&p0[i];
    u16x4 a1 = *(const u16x4*)&p1[i];
    float4 v;
    v.x = xv.x + bb.x + bf2f(a0[0]) + bf2f(a1[0]);
    v.y = xv.y + bb.y + bf2f(a0[1]) + bf2f(a1[1]);
    v.z = xv.z + bb.z + bf2f(a0[2]) + bf2f(a1[2]);
    v.w = xv.w + bb.w + bf2f(a0[3]) + bf2f(a1[3]);
    *(float4*)&xmid[i] = v;
    float sum = v.x + v.y + v.z + v.w;
    float sq  = v.x * v.x + v.y * v.y + v.z * v.z + v.w * v.w;
#pragma unroll
    for (int off = 1; off < 64; off <<= 1) {
        sum += __shfl_xor(sum, off);
        sq  += __shfl_xor(sq,  off);
    }
    __shared__ float s1[4], s2[4];
    int wave = t >> 6;
    if ((t & 63) == 0) { s1[wave] = sum; s2[wave] = sq; }
    __syncthreads();
    sum = s1[0] + s1[1] + s1[2] + s1[3];
    sq  = s2[0] + s2[1] + s2[2] + s2[3];
    float mean = sum * (1.0f / 1024.0f);
    float var  = sq  * (1.0f / 1024.0f) - mean * mean;
    float inv  = rsqrtf(var + 1e-6f);
    float4 sc = ((const float4*)s)[t], lb = ((const float4*)b)[t];
    u16x4 o;
    o[0] = f2bf((v.x - mean) * inv * sc.x + lb.x);
    o[1] = f2bf((v.y - mean) * inv * sc.y + lb.y);
    o[2] = f2bf((v.z - mean) * inv * sc.z + lb.z);
    o[3] = f2bf((v.w - mean) * inv * sc.w + lb.w);
    *(u16x4*)&xn2[i] = o;
}

// ---------------- reduce: out = xmid + b3 + sum of 4 bf16 partials ----------
__global__ __launch_bounds__(256) void reduce4(const u16* __restrict__ p0,
                                               const u16* __restrict__ p1,
                                               const u16* __restrict__ p2,
                                               const u16* __restrict__ p3,
                                               const float* __restrict__ xmid,
                                               const float* __restrict__ b3,
                                               float* __restrict__ out) {
    size_t i = ((size_t)blockIdx.x * 256 + threadIdx.x) * 4;
    float4 xm = *(const float4*)&xmid[i];
    float4 bb = *(const float4*)&b3[i & 1023];
    u16x4 a0 = *(const u16x4*)&p0[i];
    u16x4 a1 = *(const u16x4*)&p1[i];
    u16x4 a2 = *(const u16x4*)&p2[i];
    u16x4 a3 = *(const u16x4*)&p3[i];
    float4 o;
    o.x = xm.x + bb.x + bf2f(a0[0]) + bf2f(a1[0]) + bf2f(a2[0]) + bf2f(a3[0]);
    o.y = xm.y + bb.y + bf2f(a0[1]) + bf2f(a1[1]) + bf2f(a2[1]) + bf2f(a3[1]);
    o.z = xm.z + bb.z + bf2f(a0[2]) + bf2f(a1[2]) + bf2f(a2[2]) + bf2f(a3[2]);
    o.w = xm.w + bb.w + bf2f(a0[3]) + bf2f(a1[3]) + bf2f(a2[3]) + bf2f(a3[3]);
    *(float4*)&out[i] = o;
}

// ---------------- Flash attention v2 ----------------------------------------
// grid (16 qt, 16 h, 4 b); 256 threads; 64-row Q tiles (16 rows/wave).
// Q frags direct from global; K staged in LDS (R0-proven); T14 async-STAGE
// split: K/V for tile kt+1 are global-loaded into REGISTERS during tile kt's
// compute phase (issued after the LDS writes, before the compute barrier), so
// only reg->LDS writes sit between the barriers — HBM/L2 latency hides under
// QK+softmax+PV. No-max softmax (|s|<=8 by QK-norm); lane-local l partials.
#define LPK 72
#define LPV 72
#define LPP 68
__global__ __launch_bounds__(256, 4) void flash(const u16* __restrict__ qkv,
                                                u16* __restrict__ o) {
    int qt = blockIdx.x, h = blockIdx.y, b = blockIdx.z;
    int tid = threadIdx.x, wave = tid >> 6, lane = tid & 63;
    int quad = lane >> 4, l15 = lane & 15;

    __shared__ u16 Ks[64 * LPK];
    __shared__ u16 Vt[64 * LPV];   // [d][key]
    __shared__ u16 Ps[64 * LPP];

    // Q A-fragments straight from global (rows wave*16+l15, 16B contiguous)
    const u16* qrow = qkv + (size_t)(b * 1024 + qt * 64 + wave * 16 + l15) * 3072
                      + h * 64 + quad * 8;
    bfrag aq0 = *(const bfrag*)qrow;
    bfrag aq1 = *(const bfrag*)(qrow + 32);

    // staging bases (tile-0 addresses; +kt*64*3072 per tile)
    int krow = tid >> 2, kseg = tid & 3;
    const u16* kbase = qkv + (size_t)(b * 1024 + krow) * 3072 + 1024
                       + h * 64 + kseg * 16;
    const u16* vbase = qkv + (size_t)(b * 1024 + lane) * 3072 + 2048
                       + h * 64 + wave * 16;

    // prologue: tile-0 K/V into registers
    u16x8 k0 = *(const u16x8*)kbase;
    u16x8 k1 = *(const u16x8*)(kbase + 8);
    u16x8 v0 = *(const u16x8*)vbase;
    u16x8 v1 = *(const u16x8*)(vbase + 8);

    f32x4 accO[4] = {};
    float l_run[4] = {0.f, 0.f, 0.f, 0.f};

    for (int kt = 0; kt < 16; kt++) {
        __syncthreads();   // prev compute done: Ks/Vt writable
        // reg -> LDS (the only work between the barriers)
        *(u16x8*)&Ks[krow * LPK + kseg * 16]     = k0;
        *(u16x8*)&Ks[krow * LPK + kseg * 16 + 8] = k1;
#pragma unroll
        for (int j = 0; j < 8; j++) Vt[(wave * 16 + j) * LPV + lane]     = v0[j];
#pragma unroll
        for (int j = 0; j < 8; j++) Vt[(wave * 16 + 8 + j) * LPV + lane] = v1[j];
        // issue next tile's loads NOW — they fly during the compute below
        if (kt < 15) {
            const u16* kn = kbase + (size_t)(kt + 1) * 64 * 3072;
            const u16* vn = vbase + (size_t)(kt + 1) * 64 * 3072;
            k0 = *(const u16x8*)kn;
            k1 = *(const u16x8*)(kn + 8);
            v0 = *(const u16x8*)vn;
            v1 = *(const u16x8*)(vn + 8);
        }
        __syncthreads();

        // S = Q x K^T over 64 keys
        f32x4 accS[4] = {};
#pragma unroll
        for (int ct = 0; ct < 4; ct++) {
            bfrag bk0 = *(const bfrag*)&Ks[(ct * 16 + l15) * LPK + quad * 8];
            bfrag bk1 = *(const bfrag*)&Ks[(ct * 16 + l15) * LPK + 32 + quad * 8];
            accS[ct] = __builtin_amdgcn_mfma_f32_16x16x32_bf16(aq0, bk0, accS[ct], 0, 0, 0);
            accS[ct] = __builtin_amdgcn_mfma_f32_16x16x32_bf16(aq1, bk1, accS[ct], 0, 0, 0);
        }

        // p = exp(s) (no max needed), lane-local l partial, write P
#pragma unroll
        for (int r = 0; r < 4; r++) {
            float p0 = __expf(accS[0][r]);
            float p1 = __expf(accS[1][r]);
            float p2 = __expf(accS[2][r]);
            float p3 = __expf(accS[3][r]);
            l_run[r] += (p0 + p1) + (p2 + p3);
            int pbase = (wave * 16 + quad * 4 + r) * LPP + l15;
            Ps[pbase + 0]  = f2bf(p0);
            Ps[pbase + 16] = f2bf(p1);
            Ps[pbase + 32] = f2bf(p2);
            Ps[pbase + 48] = f2bf(p3);
        }

        // O += P x V  (ap via two b64 reads; Vt rows give b128 B-frags)
#pragma unroll
        for (int kk = 0; kk < 2; kk++) {
            const u16* pp = &Ps[(wave * 16 + l15) * LPP + kk * 32 + quad * 8];
            u16x4 lo = *(const u16x4*)pp;
            u16x4 hi = *(const u16x4*)(pp + 4);
            u16x8 apu;
            apu[0] = lo[0]; apu[1] = lo[1]; apu[2] = lo[2]; apu[3] = lo[3];
            apu[4] = hi[0]; apu[5] = hi[1]; apu[6] = hi[2]; apu[7] = hi[3];
            bfrag ap = __builtin_bit_cast(bfrag, apu);
#pragma unroll
            for (int oc = 0; oc < 4; oc++) {
                bfrag bv = *(const bfrag*)&Vt[(oc * 16 + l15) * LPV + kk * 32 + quad * 8];
                accO[oc] = __builtin_amdgcn_mfma_f32_16x16x32_bf16(ap, bv, accO[oc], 0, 0, 0);
            }
        }
    }

    // epilogue: reduce l over the 16 row-lanes, normalize, store
#pragma unroll
    for (int r = 0; r < 4; r++) {
        float l = l_run[r];
#pragma unroll
        for (int m = 1; m < 16; m <<= 1) l += __shfl_xor(l, m);
        float linv = 1.0f / l;
        int srow = qt * 64 + wave * 16 + quad * 4 + r;
#pragma unroll
        for (int oc = 0; oc < 4; oc++)
            o[(size_t)(b * 1024 + srow) * 1024 + h * 64 + oc * 16 + l15] =
                f2bf(accO[oc][r] * linv);
    }
}

// ---------------------------------------------------------------------------
extern "C" void kernel_launch(void* const* d_in, const int* in_sizes, int n_in,
                              void* d_out, int out_size, void* d_ws, size_t ws_size,
                              hipStream_t stream) {
    const float* x     = (const float*)d_in[0];
    const float* ln1_s = (const float*)d_in[2];
    const float* ln1_b = (const float*)d_in[3];
    const float* Wq = (const float*)d_in[4];  const float* bq = (const float*)d_in[5];
    const float* Wk = (const float*)d_in[6];  const float* bk = (const float*)d_in[7];
    const float* Wv = (const float*)d_in[8];  const float* bv = (const float*)d_in[9];
    const float* qn_s = (const float*)d_in[10]; const float* qn_b = (const float*)d_in[11];
    const float* kn_s = (const float*)d_in[12]; const float* kn_b = (const float*)d_in[13];
    const float* Wo = (const float*)d_in[14]; const float* bo = (const float*)d_in[15];
    const float* ln2_s = (const float*)d_in[16]; const float* ln2_b = (const float*)d_in[17];
    const float* W1 = (const float*)d_in[18]; const float* b1 = (const float*)d_in[19];
    const float* W2 = (const float*)d_in[20]; const float* b2 = (const float*)d_in[21];
    const float* W3 = (const float*)d_in[22]; const float* b3 = (const float*)d_in[23];
    float* out = (float*)d_out;

    char* ws = (char*)d_ws;
    const size_t MB = (size_t)1 << 20;
    u16* WqkvT = (u16*)(ws + 0);         // 0..6    dead after QKV; then p0 @0
    u16* WoT   = (u16*)(ws + 6 * MB);    // 6..8    dead after Wo
    u16* W12T  = (u16*)(ws + 8 * MB);    // 8..24   dead after W12; then p1/p2
    u16* W3T   = (u16*)(ws + 24 * MB);   // 24..32  dead after splitk
    u16* xn1   = (u16*)(ws + 32 * MB);   // 32..40  dead after QKV
    u16* attn  = (u16*)(ws + 32 * MB);   //   reuse: dead after Wo-gemm
    u16* xn2   = (u16*)(ws + 32 * MB);   //   reuse: dead after W12
    u16* qkv   = (u16*)(ws + 40 * MB);   // 40..64  dead after flash
    float* xmid = (float*)(ws + 40 * MB);//   reuse: 40..56, alive until reduce4
    u16* p3    = (u16*)(ws + 56 * MB);   // 56..64
    u16* h     = (u16*)(ws + 64 * MB);   // 64..96  dead after splitk
    u16* wp0   = (u16*)(ws + 64 * MB);   // Wo partials: 64..72, 72..80
    u16* wp1   = (u16*)(ws + 72 * MB);   //   dead after reduce_ln (before h)
    u16* p0    = (u16*)(ws + 0);
    u16* p1    = (u16*)(ws + 8 * MB);
    u16* p2    = (u16*)(ws + 16 * MB);
    // peak = 96 MB

    wtln<<<8192, 256, 0, stream>>>(Wq, Wk, Wv, Wo, W1, W2, W3,
                                   WqkvT, WoT, W12T, W3T,
                                   x, ln1_s, ln1_b, xn1);

    // fused QKV + per-head QK-norm (BK=64)
    gemm64<4><<<dim3(24, 32, 1), 256, 0, stream>>>(
        xn1, WqkvT, bq, bk, bv, qn_s, qn_b, kn_s, kn_b,
        qkv, nullptr, nullptr, nullptr, 4096, 3072, 1024, 1024);

    flash<<<dim3(16, 16, 4), 256, 0, stream>>>(qkv, attn);

    // Wo split-K=2 partials (BK=64)
    gemm64<0><<<dim3(8, 32, 2), 256, 0, stream>>>(
        attn, WoT, nullptr, nullptr, nullptr, nullptr, nullptr, nullptr, nullptr,
        wp0, wp1, nullptr, nullptr, 4096, 1024, 1024, 512);

    // xmid = x + bo + wp0 + wp1; xn2 = LN2(xmid)
    reduce_ln<<<4096, 256, 0, stream>>>(wp0, wp1, x, bo, ln2_s, ln2_b, xmid, xn2);

    // fused GeGLU FFN (BK=64)
    gemm_w12<<<dim3(32, 32), 256, 0, stream>>>(xn2, W12T, b1, b2, h);

    // W3 split-K=4 partials (BK=64)
    gemm64<0><<<dim3(8, 32, 4), 256, 0, stream>>>(
        h, W3T, nullptr, nullptr, nullptr, nullptr, nullptr, nullptr, nullptr,
        p0, p1, p2, p3, 4096, 1024, 4096, 1024);

    // out = xmid + b3 + sum(partials)
    reduce4<<<4096, 256, 0, stream>>>(p0, p1, p2, p3, xmid, b3, out);
}

// Round 7
// 380.643 us; speedup vs baseline: 1.1727x; 1.0458x over previous
//
#include <hip/hip_runtime.h>

typedef unsigned short u16;
typedef __bf16  bfrag  __attribute__((ext_vector_type(8)));   // MFMA A/B operand (4 VGPRs)
typedef float   f32x4  __attribute__((ext_vector_type(4)));   // MFMA C/D operand
typedef u16     u16x8  __attribute__((ext_vector_type(8)));
typedef u16     u16x4  __attribute__((ext_vector_type(4)));

__device__ __forceinline__ float bf2f(u16 u) {
    unsigned v = ((unsigned)u) << 16;
    return __builtin_bit_cast(float, v);
}
__device__ __forceinline__ u16 f2bf(float f) {   // round-to-nearest-even
    unsigned x = __builtin_bit_cast(unsigned, f);
    unsigned r = (x + 0x7fffu + ((x >> 16) & 1u)) >> 16;
    return (u16)r;
}
__device__ __forceinline__ void g2l16(const u16* g, u16* l) {
    // 16B per lane -> lds_base + lane*16 (wave-uniform LDS base)
    __builtin_amdgcn_global_load_lds((__attribute__((address_space(1))) void*)g,
                                     (__attribute__((address_space(3))) void*)l, 16, 0, 0);
}
__device__ __forceinline__ float gelu_tanh(float x) {
    // 0.5x(1+tanh(c)) == x * sigmoid(2c)
    float c = 1.5957691216057308f * (x + 0.044715f * x * x * x);
    return x * __frcp_rn(1.0f + __expf(-c));
}

// BK=64 LDS tiles: row = 128 B = 8 chunks of 16 B = exactly one 32-bank stripe.
// Swizzle phys_chunk = logical_chunk ^ (row & 7): conflict-free frag reads.
#define SW64(l)   (((((l) & 7) ^ (((l) >> 3) & 7))) * 8)
#define RS64(kk, quad, l15)  (((((kk) * 4 + (quad)) ^ ((l15) & 7))) * 8)

// ---------------- weight transposes + LN1 fused in ONE kernel ---------------
// 64x64 fp32 tiles; transpose via padded LDS; each thread WRITES 16
// contiguous bf16 (2 x 16B stores) -> full store coalescing.
__global__ __launch_bounds__(256) void wtln(
        const float* __restrict__ Wq, const float* __restrict__ Wk,
        const float* __restrict__ Wv, const float* __restrict__ Wo,
        const float* __restrict__ W1, const float* __restrict__ W2,
        const float* __restrict__ W3,
        u16* __restrict__ WqkvT, u16* __restrict__ WoT,
        u16* __restrict__ W12T, u16* __restrict__ W3T,
        const float* __restrict__ x, const float* __restrict__ ln1_s,
        const float* __restrict__ ln1_b, u16* __restrict__ xn1) {
    __shared__ float tile[64][65];
    int blk = blockIdx.x;
    if (blk >= 4096) {
        int row = blk - 4096, t = threadIdx.x;
        float4 v = ((const float4*)(x + (size_t)row * 1024))[t];
        float sum = v.x + v.y + v.z + v.w;
        float sq  = v.x * v.x + v.y * v.y + v.z * v.z + v.w * v.w;
#pragma unroll
        for (int off = 1; off < 64; off <<= 1) {
            sum += __shfl_xor(sum, off);
            sq  += __shfl_xor(sq,  off);
        }
        float* s1 = &tile[0][0];
        float* s2 = &tile[0][8];
        int wave = t >> 6;
        if ((t & 63) == 0) { s1[wave] = sum; s2[wave] = sq; }
        __syncthreads();
        sum = s1[0] + s1[1] + s1[2] + s1[3];
        sq  = s2[0] + s2[1] + s2[2] + s2[3];
        float mean = sum * (1.0f / 1024.0f);
        float var  = sq  * (1.0f / 1024.0f) - mean * mean;
        float inv  = rsqrtf(var + 1e-6f);
        float4 sc = ((const float4*)ln1_s)[t], bb = ((const float4*)ln1_b)[t];
        u16x4 o;
        o[0] = f2bf((v.x - mean) * inv * sc.x + bb.x);
        o[1] = f2bf((v.y - mean) * inv * sc.y + bb.y);
        o[2] = f2bf((v.z - mean) * inv * sc.z + bb.z);
        o[3] = f2bf((v.w - mean) * inv * sc.w + bb.w);
        *(u16x4*)&xn1[(size_t)row * 1024 + t * 4] = o;
        return;
    }
    const float* W; u16* Wt; int R, C, local;
    if (blk < 768) {
        int w = blk >> 8; local = blk & 255;
        W = (w == 0) ? Wq : (w == 1) ? Wk : Wv;
        Wt = WqkvT + (size_t)w * 1024 * 1024; R = 1024; C = 1024;
    } else if (blk < 1024) { W = Wo; Wt = WoT; R = 1024; C = 1024; local = blk - 768; }
    else if (blk < 2048)   { W = W1; Wt = W12T; R = 1024; C = 4096; local = blk - 1024; }
    else if (blk < 3072)   { W = W2; Wt = W12T + (size_t)4096 * 1024; R = 1024; C = 4096; local = blk - 2048; }
    else                   { W = W3; Wt = W3T; R = 4096; C = 1024; local = blk - 3072; }
    int tiles_x = C >> 6;
    int c0 = (local % tiles_x) * 64, r0 = (local / tiles_x) * 64;
    int t = threadIdx.x;
    int lr = t >> 4, lc = (t & 15) * 4;
#pragma unroll
    for (int p = 0; p < 4; p++) {
        float4 v = *(const float4*)&W[(size_t)(r0 + p * 16 + lr) * C + c0 + lc];
        *(float4*)&tile[p * 16 + lr][lc] = v;
    }
    __syncthreads();
    int oc = t >> 2;            // output row = source col (0..63)
    int rs = (t & 3) * 16;      // 16-wide r segment
    u16x8 o0, o1;
#pragma unroll
    for (int j = 0; j < 8; j++) o0[j] = f2bf(tile[rs + j][oc]);
#pragma unroll
    for (int j = 0; j < 8; j++) o1[j] = f2bf(tile[rs + 8 + j][oc]);
    u16* dst = &Wt[(size_t)(c0 + oc) * R + r0 + rs];
    *(u16x8*)dst       = o0;
    *(u16x8*)(dst + 8) = o1;
}

// ---- gemm64: 4-wave 128x128 block tile, 64x64 wave tile, BK=64 -------------
// EPI 0: bf16 partial store to o[kz] (split-K) | 4: QKV + per-head LN.
// Split-K may be UNEVEN: last z-slice covers K - kz*Klen (enables split-K=3
// on K=4096: 1344/1344/1408, all multiples of 64).
template <int EPI>
__global__ __launch_bounds__(256, 3) void gemm64(const u16* __restrict__ A,
                                                 const u16* __restrict__ Bt,
                                                 const float* __restrict__ bias,
                                                 const float* __restrict__ bias2,
                                                 const float* __restrict__ bias3,
                                                 const float* __restrict__ qn_s,
                                                 const float* __restrict__ qn_b,
                                                 const float* __restrict__ kn_s,
                                                 const float* __restrict__ kn_b,
                                                 u16* __restrict__ o0,
                                                 u16* __restrict__ o1,
                                                 u16* __restrict__ o2,
                                                 u16* __restrict__ o3,
                                                 int M, int N, int K, int Klen) {
    __shared__ u16 As[128 * 64];
    __shared__ u16 Bs[128 * 64];
    int tid = threadIdx.x, wave = tid >> 6, lane = tid & 63;
    int quad = lane >> 4, l15 = lane & 15;
    int row0 = blockIdx.y * 128, col0 = blockIdx.x * 128;
    int kz = blockIdx.z;
    int klen = (kz == (int)gridDim.z - 1) ? K - kz * Klen : Klen;
    int wr = (wave >> 1) * 64, wc = (wave & 1) * 64;
    int swz = SW64(lane);

    f32x4 acc[4][4] = {};

    const u16* gA = A  + (size_t)(row0 + wave * 32 + (lane >> 3)) * K + kz * Klen + swz;
    const u16* gB = Bt + (size_t)(col0 + wave * 32 + (lane >> 3)) * K + kz * Klen + swz;
    u16* lA = &As[wave * 32 * 64];
    u16* lB = &Bs[wave * 32 * 64];

    for (int k0 = 0; k0 < klen; k0 += 64) {
        __syncthreads();
#pragma unroll
        for (int j = 0; j < 4; j++) {
            g2l16(gA + k0 + j * 8 * K, lA + j * 8 * 64);
            g2l16(gB + k0 + j * 8 * K, lB + j * 8 * 64);
        }
        __syncthreads();
#pragma unroll
        for (int kk = 0; kk < 2; kk++) {
            int rs = RS64(kk, quad, l15);
            bfrag af[4], bf[4];
#pragma unroll
            for (int mi = 0; mi < 4; mi++)
                af[mi] = *(const bfrag*)&As[(wr + mi * 16 + l15) * 64 + rs];
#pragma unroll
            for (int ni = 0; ni < 4; ni++)
                bf[ni] = *(const bfrag*)&Bs[(wc + ni * 16 + l15) * 64 + rs];
#pragma unroll
            for (int mi = 0; mi < 4; mi++)
#pragma unroll
                for (int ni = 0; ni < 4; ni++)
                    acc[mi][ni] = __builtin_amdgcn_mfma_f32_16x16x32_bf16(
                        af[mi], bf[ni], acc[mi][ni], 0, 0, 0);
        }
    }

    if (EPI == 0) {
        u16* P = (kz == 0) ? o0 : (kz == 1) ? o1 : (kz == 2) ? o2 : o3;
#pragma unroll
        for (int mi = 0; mi < 4; mi++) {
            int rbase = row0 + wr + mi * 16 + quad * 4;
#pragma unroll
            for (int r = 0; r < 4; r++)
#pragma unroll
                for (int ni = 0; ni < 4; ni++)
                    P[(size_t)(rbase + r) * N + col0 + wc + ni * 16 + l15] =
                        f2bf(acc[mi][ni][r]);
        }
    } else {
        int cbase = col0 + wc;
        int z = cbase >> 10;              // 0=q, 1=k, 2=v
        int hd = (cbase >> 6) & 15;
        const float* bp = (z == 0) ? bias : (z == 1) ? bias2 : bias3;
        float post = (z == 0) ? 0.125f : 1.0f;
        float bv[4], sn[4], bn[4];
#pragma unroll
        for (int ni = 0; ni < 4; ni++)
            bv[ni] = bp[(cbase & 1023) + ni * 16 + l15];
        if (z < 2) {
            const float* ns = (z == 0) ? qn_s : kn_s;
            const float* nb = (z == 0) ? qn_b : kn_b;
#pragma unroll
            for (int ni = 0; ni < 4; ni++) {
                sn[ni] = ns[hd * 64 + ni * 16 + l15];
                bn[ni] = nb[hd * 64 + ni * 16 + l15];
            }
        }
#pragma unroll
        for (int mi = 0; mi < 4; mi++) {
            int rbase = row0 + wr + mi * 16 + quad * 4;
#pragma unroll
            for (int r = 0; r < 4; r++) {
                float v0 = acc[mi][0][r] + bv[0];
                float v1 = acc[mi][1][r] + bv[1];
                float v2 = acc[mi][2][r] + bv[2];
                float v3 = acc[mi][3][r] + bv[3];
                size_t rb = (size_t)(rbase + r) * N + cbase;
                if (z == 2) {
                    o0[rb + 0 * 16 + l15] = f2bf(v0);
                    o0[rb + 1 * 16 + l15] = f2bf(v1);
                    o0[rb + 2 * 16 + l15] = f2bf(v2);
                    o0[rb + 3 * 16 + l15] = f2bf(v3);
                } else {
                    float s  = v0 + v1 + v2 + v3;
                    float sq = v0 * v0 + v1 * v1 + v2 * v2 + v3 * v3;
#pragma unroll
                    for (int m = 1; m < 16; m <<= 1) {
                        s  += __shfl_xor(s,  m);
                        sq += __shfl_xor(sq, m);
                    }
                    float mean = s * (1.0f / 64.0f);
                    float var  = sq * (1.0f / 64.0f) - mean * mean;
                    float inv  = rsqrtf(var + 1e-6f);
                    o0[rb + 0 * 16 + l15] = f2bf(((v0 - mean) * inv * sn[0] + bn[0]) * post);
                    o0[rb + 1 * 16 + l15] = f2bf(((v1 - mean) * inv * sn[1] + bn[1]) * post);
                    o0[rb + 2 * 16 + l15] = f2bf(((v2 - mean) * inv * sn[2] + bn[2]) * post);
                    o0[rb + 3 * 16 + l15] = f2bf(((v3 - mean) * inv * sn[3] + bn[3]) * post);
                }
            }
        }
    }
}

// ---------------- fused GeGLU FFN GEMM, BK=64 (R0-proven form) --------------
__global__ __launch_bounds__(256, 2) void gemm_w12(const u16* __restrict__ A,
                                                   const u16* __restrict__ W12T,
                                                   const float* __restrict__ b1,
                                                   const float* __restrict__ b2,
                                                   u16* __restrict__ H) {
    __shared__ u16 As[128 * 64];
    __shared__ u16 B1s[128 * 64];
    __shared__ u16 B2s[128 * 64];
    int tid = threadIdx.x, wave = tid >> 6, lane = tid & 63;
    int quad = lane >> 4, l15 = lane & 15;
    int row0 = blockIdx.y * 128, col0 = blockIdx.x * 128;
    int wr = (wave >> 1) * 64, wc = (wave & 1) * 64;
    int swz = SW64(lane);

    f32x4 acc1[4][4] = {}, acc2[4][4] = {};

    const u16* gA  = A    + (size_t)(row0 + wave * 32 + (lane >> 3)) * 1024 + swz;
    const u16* gB1 = W12T + (size_t)(col0 + wave * 32 + (lane >> 3)) * 1024 + swz;
    const u16* gB2 = gB1  + (size_t)4096 * 1024;
    u16* lA  = &As [wave * 32 * 64];
    u16* lB1 = &B1s[wave * 32 * 64];
    u16* lB2 = &B2s[wave * 32 * 64];

    for (int k0 = 0; k0 < 1024; k0 += 64) {
        __syncthreads();
#pragma unroll
        for (int j = 0; j < 4; j++) {
            g2l16(gA  + k0 + j * 8 * 1024, lA  + j * 8 * 64);
            g2l16(gB1 + k0 + j * 8 * 1024, lB1 + j * 8 * 64);
            g2l16(gB2 + k0 + j * 8 * 1024, lB2 + j * 8 * 64);
        }
        __syncthreads();
#pragma unroll
        for (int kk = 0; kk < 2; kk++) {
            int rs = RS64(kk, quad, l15);
            bfrag af[4], b1f[4], b2f[4];
#pragma unroll
            for (int mi = 0; mi < 4; mi++)
                af[mi] = *(const bfrag*)&As[(wr + mi * 16 + l15) * 64 + rs];
#pragma unroll
            for (int ni = 0; ni < 4; ni++) {
                b1f[ni] = *(const bfrag*)&B1s[(wc + ni * 16 + l15) * 64 + rs];
                b2f[ni] = *(const bfrag*)&B2s[(wc + ni * 16 + l15) * 64 + rs];
            }
#pragma unroll
            for (int mi = 0; mi < 4; mi++)
#pragma unroll
                for (int ni = 0; ni < 4; ni++) {
                    acc1[mi][ni] = __builtin_amdgcn_mfma_f32_16x16x32_bf16(
                        af[mi], b1f[ni], acc1[mi][ni], 0, 0, 0);
                    acc2[mi][ni] = __builtin_amdgcn_mfma_f32_16x16x32_bf16(
                        af[mi], b2f[ni], acc2[mi][ni], 0, 0, 0);
                }
        }
    }

    float bv1[4], bv2[4];
    int cols[4];
#pragma unroll
    for (int ni = 0; ni < 4; ni++) {
        cols[ni] = col0 + wc + ni * 16 + l15;
        bv1[ni] = b1[cols[ni]];
        bv2[ni] = b2[cols[ni]];
    }
#pragma unroll
    for (int mi = 0; mi < 4; mi++) {
        int rbase = row0 + wr + mi * 16 + quad * 4;
#pragma unroll
        for (int r = 0; r < 4; r++) {
#pragma unroll
            for (int ni = 0; ni < 4; ni++) {
                float x1 = acc1[mi][ni][r] + bv1[ni];
                float x2 = acc2[mi][ni][r] + bv2[ni];
                H[(size_t)(rbase + r) * 4096 + cols[ni]] = f2bf(x1 * gelu_tanh(x2));
            }
        }
    }
}

// ---- fused Wo-reduce + residual + LN2 --------------------------------------
__global__ __launch_bounds__(256) void reduce_ln(const u16* __restrict__ p0,
                                                 const u16* __restrict__ p1,
                                                 const float* __restrict__ x,
                                                 const float* __restrict__ bo,
                                                 const float* __restrict__ s,
                                                 const float* __restrict__ b,
                                                 float* __restrict__ xmid,
                                                 u16* __restrict__ xn2) {
    int row = blockIdx.x, t = threadIdx.x;
    size_t i = (size_t)row * 1024 + t * 4;
    float4 xv = *(const float4*)&x[i];
    float4 bb = *(const float4*)&bo[t * 4];
    u16x4 a0 = *(const u16x4*)&p0[i];
    u16x4 a1 = *(const u16x4*)&p1[i];
    float4 v;
    v.x = xv.x + bb.x + bf2f(a0[0]) + bf2f(a1[0]);
    v.y = xv.y + bb.y + bf2f(a0[1]) + bf2f(a1[1]);
    v.z = xv.z + bb.z + bf2f(a0[2]) + bf2f(a1[2]);
    v.w = xv.w + bb.w + bf2f(a0[3]) + bf2f(a1[3]);
    *(float4*)&xmid[i] = v;
    float sum = v.x + v.y + v.z + v.w;
    float sq  = v.x * v.x + v.y * v.y + v.z * v.z + v.w * v.w;
#pragma unroll
    for (int off = 1; off < 64; off <<= 1) {
        sum += __shfl_xor(sum, off);
        sq  += __shfl_xor(sq,  off);
    }
    __shared__ float s1[4], s2[4];
    int wave = t >> 6;
    if ((t & 63) == 0) { s1[wave] = sum; s2[wave] = sq; }
    __syncthreads();
    sum = s1[0] + s1[1] + s1[2] + s1[3];
    sq  = s2[0] + s2[1] + s2[2] + s2[3];
    float mean = sum * (1.0f / 1024.0f);
    float var  = sq  * (1.0f / 1024.0f) - mean * mean;
    float inv  = rsqrtf(var + 1e-6f);
    float4 sc = ((const float4*)s)[t], lb = ((const float4*)b)[t];
    u16x4 o;
    o[0] = f2bf((v.x - mean) * inv * sc.x + lb.x);
    o[1] = f2bf((v.y - mean) * inv * sc.y + lb.y);
    o[2] = f2bf((v.z - mean) * inv * sc.z + lb.z);
    o[3] = f2bf((v.w - mean) * inv * sc.w + lb.w);
    *(u16x4*)&xn2[i] = o;
}

// ---------------- reduce: out = xmid + b3 + sum of 3 bf16 partials ----------
__global__ __launch_bounds__(256) void reduce3(const u16* __restrict__ p0,
                                               const u16* __restrict__ p1,
                                               const u16* __restrict__ p2,
                                               const float* __restrict__ xmid,
                                               const float* __restrict__ b3,
                                               float* __restrict__ out) {
    size_t i = ((size_t)blockIdx.x * 256 + threadIdx.x) * 4;
    float4 xm = *(const float4*)&xmid[i];
    float4 bb = *(const float4*)&b3[i & 1023];
    u16x4 a0 = *(const u16x4*)&p0[i];
    u16x4 a1 = *(const u16x4*)&p1[i];
    u16x4 a2 = *(const u16x4*)&p2[i];
    float4 o;
    o.x = xm.x + bb.x + bf2f(a0[0]) + bf2f(a1[0]) + bf2f(a2[0]);
    o.y = xm.y + bb.y + bf2f(a0[1]) + bf2f(a1[1]) + bf2f(a2[1]);
    o.z = xm.z + bb.z + bf2f(a0[2]) + bf2f(a1[2]) + bf2f(a2[2]);
    o.w = xm.w + bb.w + bf2f(a0[3]) + bf2f(a1[3]) + bf2f(a2[3]);
    *(float4*)&out[i] = o;
}

// ---------------- Flash attention v2, Q-tile 128 ----------------------------
// grid (8 qt, 16 h, 4 b); 256 threads; 128-row Q tiles: each wave owns TWO
// 16-row groups (g=0,1) sharing one K/V staging -> fixed per-tile costs
// (K stage, V scalar-transpose, 2 barriers) amortize over 2x FLOPs, and total
// K/V global re-reads halve (8 qt blocks vs 16). K frags hoisted to registers
// once per tile, reused by both groups. T14 async-STAGE: next tile's K/V
// global-loaded into regs during compute. No-max softmax (|s|<=8 by QK-norm).
#define LPK 72
#define LPV 72
#define LPP 68
__global__ __launch_bounds__(256, 2) void flash(const u16* __restrict__ qkv,
                                                u16* __restrict__ o) {
    int qt = blockIdx.x, h = blockIdx.y, b = blockIdx.z;
    int tid = threadIdx.x, wave = tid >> 6, lane = tid & 63;
    int quad = lane >> 4, l15 = lane & 15;

    __shared__ u16 Ks[64 * LPK];
    __shared__ u16 Vt[64 * LPV];    // [d][key]
    __shared__ u16 Ps[128 * LPP];   // two 64-row halves, one per group

    // Q A-fragments straight from global, two row-groups per wave
    bfrag aq[2][2];
#pragma unroll
    for (int g = 0; g < 2; g++) {
        const u16* qrow = qkv
            + (size_t)(b * 1024 + qt * 128 + g * 64 + wave * 16 + l15) * 3072
            + h * 64 + quad * 8;
        aq[g][0] = *(const bfrag*)qrow;
        aq[g][1] = *(const bfrag*)(qrow + 32);
    }

    // staging bases (tile-0 addresses; +kt*64*3072 per tile)
    int krow = tid >> 2, kseg = tid & 3;
    const u16* kbase = qkv + (size_t)(b * 1024 + krow) * 3072 + 1024
                       + h * 64 + kseg * 16;
    const u16* vbase = qkv + (size_t)(b * 1024 + lane) * 3072 + 2048
                       + h * 64 + wave * 16;

    // prologue: tile-0 K/V into registers
    u16x8 k0 = *(const u16x8*)kbase;
    u16x8 k1 = *(const u16x8*)(kbase + 8);
    u16x8 v0 = *(const u16x8*)vbase;
    u16x8 v1 = *(const u16x8*)(vbase + 8);

    f32x4 accO[2][4] = {};
    float l_run[2][4] = {};

    for (int kt = 0; kt < 16; kt++) {
        __syncthreads();   // prev compute done: Ks/Vt writable
        // reg -> LDS (the only work between the barriers)
        *(u16x8*)&Ks[krow * LPK + kseg * 16]     = k0;
        *(u16x8*)&Ks[krow * LPK + kseg * 16 + 8] = k1;
#pragma unroll
        for (int j = 0; j < 8; j++) Vt[(wave * 16 + j) * LPV + lane]     = v0[j];
#pragma unroll
        for (int j = 0; j < 8; j++) Vt[(wave * 16 + 8 + j) * LPV + lane] = v1[j];
        // issue next tile's loads NOW — they fly during the compute below
        if (kt < 15) {
            const u16* kn = kbase + (size_t)(kt + 1) * 64 * 3072;
            const u16* vn = vbase + (size_t)(kt + 1) * 64 * 3072;
            k0 = *(const u16x8*)kn;
            k1 = *(const u16x8*)(kn + 8);
            v0 = *(const u16x8*)vn;
            v1 = *(const u16x8*)(vn + 8);
        }
        __syncthreads();

        // K B-fragments once per tile, reused by both Q groups
        bfrag bkf[4][2];
#pragma unroll
        for (int ct = 0; ct < 4; ct++) {
            bkf[ct][0] = *(const bfrag*)&Ks[(ct * 16 + l15) * LPK + quad * 8];
            bkf[ct][1] = *(const bfrag*)&Ks[(ct * 16 + l15) * LPK + 32 + quad * 8];
        }

#pragma unroll
        for (int g = 0; g < 2; g++) {
            // S = Q x K^T over 64 keys
            f32x4 accS[4] = {};
#pragma unroll
            for (int ct = 0; ct < 4; ct++) {
                accS[ct] = __builtin_amdgcn_mfma_f32_16x16x32_bf16(
                    aq[g][0], bkf[ct][0], accS[ct], 0, 0, 0);
                accS[ct] = __builtin_amdgcn_mfma_f32_16x16x32_bf16(
                    aq[g][1], bkf[ct][1], accS[ct], 0, 0, 0);
            }

            // p = exp(s) (no max needed), lane-local l partial, write P
#pragma unroll
            for (int r = 0; r < 4; r++) {
                float p0 = __expf(accS[0][r]);
                float p1 = __expf(accS[1][r]);
                float p2 = __expf(accS[2][r]);
                float p3 = __expf(accS[3][r]);
                l_run[g][r] += (p0 + p1) + (p2 + p3);
                int pbase = (g * 64 + wave * 16 + quad * 4 + r) * LPP + l15;
                Ps[pbase + 0]  = f2bf(p0);
                Ps[pbase + 16] = f2bf(p1);
                Ps[pbase + 32] = f2bf(p2);
                Ps[pbase + 48] = f2bf(p3);
            }

            // O += P x V  (ap via two b64 reads; Vt rows give b128 B-frags)
#pragma unroll
            for (int kk = 0; kk < 2; kk++) {
                const u16* pp = &Ps[(g * 64 + wave * 16 + l15) * LPP
                                    + kk * 32 + quad * 8];
                u16x4 lo = *(const u16x4*)pp;
                u16x4 hi = *(const u16x4*)(pp + 4);
                u16x8 apu;
                apu[0] = lo[0]; apu[1] = lo[1]; apu[2] = lo[2]; apu[3] = lo[3];
                apu[4] = hi[0]; apu[5] = hi[1]; apu[6] = hi[2]; apu[7] = hi[3];
                bfrag ap = __builtin_bit_cast(bfrag, apu);
#pragma unroll
                for (int oc = 0; oc < 4; oc++) {
                    bfrag bv = *(const bfrag*)&Vt[(oc * 16 + l15) * LPV
                                                  + kk * 32 + quad * 8];
                    accO[g][oc] = __builtin_amdgcn_mfma_f32_16x16x32_bf16(
                        ap, bv, accO[g][oc], 0, 0, 0);
                }
            }
        }
    }

    // epilogue: reduce l over the 16 row-lanes, normalize, store
#pragma unroll
    for (int g = 0; g < 2; g++)
#pragma unroll
    for (int r = 0; r < 4; r++) {
        float l = l_run[g][r];
#pragma unroll
        for (int m = 1; m < 16; m <<= 1) l += __shfl_xor(l, m);
        float linv = 1.0f / l;
        int srow = qt * 128 + g * 64 + wave * 16 + quad * 4 + r;
#pragma unroll
        for (int oc = 0; oc < 4; oc++)
            o[(size_t)(b * 1024 + srow) * 1024 + h * 64 + oc * 16 + l15] =
                f2bf(accO[g][oc][r] * linv);
    }
}

// ---------------------------------------------------------------------------
extern "C" void kernel_launch(void* const* d_in, const int* in_sizes, int n_in,
                              void* d_out, int out_size, void* d_ws, size_t ws_size,
                              hipStream_t stream) {
    const float* x     = (const float*)d_in[0];
    const float* ln1_s = (const float*)d_in[2];
    const float* ln1_b = (const float*)d_in[3];
    const float* Wq = (const float*)d_in[4];  const float* bq = (const float*)d_in[5];
    const float* Wk = (const float*)d_in[6];  const float* bk = (const float*)d_in[7];
    const float* Wv = (const float*)d_in[8];  const float* bv = (const float*)d_in[9];
    const float* qn_s = (const float*)d_in[10]; const float* qn_b = (const float*)d_in[11];
    const float* kn_s = (const float*)d_in[12]; const float* kn_b = (const float*)d_in[13];
    const float* Wo = (const float*)d_in[14]; const float* bo = (const float*)d_in[15];
    const float* ln2_s = (const float*)d_in[16]; const float* ln2_b = (const float*)d_in[17];
    const float* W1 = (const float*)d_in[18]; const float* b1 = (const float*)d_in[19];
    const float* W2 = (const float*)d_in[20]; const float* b2 = (const float*)d_in[21];
    const float* W3 = (const float*)d_in[22]; const float* b3 = (const float*)d_in[23];
    float* out = (float*)d_out;

    char* ws = (char*)d_ws;
    const size_t MB = (size_t)1 << 20;
    u16* WqkvT = (u16*)(ws + 0);         // 0..6    dead after QKV; then p0 @0
    u16* WoT   = (u16*)(ws + 6 * MB);    // 6..8    dead after Wo
    u16* W12T  = (u16*)(ws + 8 * MB);    // 8..24   dead after W12; then p1/p2
    u16* W3T   = (u16*)(ws + 24 * MB);   // 24..32  dead after splitk
    u16* xn1   = (u16*)(ws + 32 * MB);   // 32..40  dead after QKV
    u16* attn  = (u16*)(ws + 32 * MB);   //   reuse: dead after Wo-gemm
    u16* xn2   = (u16*)(ws + 32 * MB);   //   reuse: dead after W12
    u16* qkv   = (u16*)(ws + 40 * MB);   // 40..64  dead after flash
    float* xmid = (float*)(ws + 40 * MB);//   reuse: 40..56, alive until reduce3
    u16* h     = (u16*)(ws + 64 * MB);   // 64..96  dead after splitk
    u16* wp0   = (u16*)(ws + 64 * MB);   // Wo partials: 64..72, 72..80
    u16* wp1   = (u16*)(ws + 72 * MB);   //   dead after reduce_ln (before h)
    u16* p0    = (u16*)(ws + 0);         // W3 partials (split-K=3)
    u16* p1    = (u16*)(ws + 8 * MB);
    u16* p2    = (u16*)(ws + 16 * MB);
    // peak = 96 MB

    wtln<<<8192, 256, 0, stream>>>(Wq, Wk, Wv, Wo, W1, W2, W3,
                                   WqkvT, WoT, W12T, W3T,
                                   x, ln1_s, ln1_b, xn1);

    // fused QKV + per-head QK-norm (BK=64)
    gemm64<4><<<dim3(24, 32, 1), 256, 0, stream>>>(
        xn1, WqkvT, bq, bk, bv, qn_s, qn_b, kn_s, kn_b,
        qkv, nullptr, nullptr, nullptr, 4096, 3072, 1024, 1024);

    flash<<<dim3(8, 16, 4), 256, 0, stream>>>(qkv, attn);

    // Wo split-K=2 partials (BK=64)
    gemm64<0><<<dim3(8, 32, 2), 256, 0, stream>>>(
        attn, WoT, nullptr, nullptr, nullptr, nullptr, nullptr, nullptr, nullptr,
        wp0, wp1, nullptr, nullptr, 4096, 1024, 1024, 512);

    // xmid = x + bo + wp0 + wp1; xn2 = LN2(xmid)
    reduce_ln<<<4096, 256, 0, stream>>>(wp0, wp1, x, bo, ln2_s, ln2_b, xmid, xn2);

    // fused GeGLU FFN (BK=64)
    gemm_w12<<<dim3(32, 32), 256, 0, stream>>>(xn2, W12T, b1, b2, h);

    // W3 split-K=3 partials (uneven: 1344/1344/1408), 768 blocks = one full
    // wave at 3 blocks/CU (split-K=4's 1024 blocks left a 256-block tail)
    gemm64<0><<<dim3(8, 32, 3), 256, 0, stream>>>(
        h, W3T, nullptr, nullptr, nullptr, nullptr, nullptr, nullptr, nullptr,
        p0, p1, p2, nullptr, 4096, 1024, 4096, 1344);

    // out = xmid + b3 + sum(partials)
    reduce3<<<4096, 256, 0, stream>>>(p0, p1, p2, xmid, b3, out);
}